// Round 1
// 1932.846 us; speedup vs baseline: 1.1135x; 1.1135x over previous
//
#include <hip/hip_runtime.h>
#include <cstddef>

// ---------------------------------------------------------------------------
// SparseAttnLayer: BN1 -> window QKV GEMM -> 16-head windowed attention
// -> proj GEMM -> scrambled window_reverse residual -> BN2 -> MLP(1x1 convs,
// exact GELU) -> residual.  All GEMMs: bf16 MFMA 16x16x32, fp32 accum.
// ---------------------------------------------------------------------------

typedef unsigned short ushort_t;
typedef __attribute__((ext_vector_type(8))) short short8;   // 8 bf16 (4 VGPRs)
typedef __attribute__((ext_vector_type(4))) float float4v;  // MFMA acc

__device__ __forceinline__ float bf2f(unsigned short h) {
  union { unsigned int u; float f; } c; c.u = ((unsigned int)h) << 16; return c.f;
}
__device__ __forceinline__ unsigned short f2bf(float f) {
  union { float f; unsigned int u; } c; c.f = f;
  unsigned int u = c.u;
  unsigned int r = u + 0x7fffu + ((u >> 16) & 1u);   // RNE
  return (unsigned short)(r >> 16);
}
__device__ __forceinline__ void async16(const void* g, void* l) {
  __builtin_amdgcn_global_load_lds(
      (const __attribute__((address_space(1))) unsigned int*)g,
      (__attribute__((address_space(3))) unsigned int*)l, 16, 0, 0);
}

// ---------------------------------------------------------------------------
// Weight prep: Bt[n][k] = W[k][n] (bf16);  plain cast for (o,c)-layout weights
// ---------------------------------------------------------------------------
__global__ void transpose_cast(const float* __restrict__ W, ushort_t* __restrict__ Wt,
                               int K, int N) {
  int idx = blockIdx.x * 256 + threadIdx.x;
  if (idx >= K * N) return;
  int nn = idx / K, kk = idx - nn * K;
  Wt[idx] = f2bf(W[(size_t)kk * N + nn]);
}
__global__ void cast_bf(const float* __restrict__ W, ushort_t* __restrict__ Wt, int total) {
  int idx = blockIdx.x * 256 + threadIdx.x;
  if (idx < total) Wt[idx] = f2bf(W[idx]);
}

// ---------------------------------------------------------------------------
// BN1 + window partition + bf16 cast: A0[(win*64+n)][c]
// block = (window, 32-channel chunk); LDS transpose for coalesced writes
// ---------------------------------------------------------------------------
__global__ __launch_bounds__(256) void prep_qkv(
    const float* __restrict__ x, const float* __restrict__ gamma,
    const float* __restrict__ beta, const float* __restrict__ mean,
    const float* __restrict__ var, ushort_t* __restrict__ A0) {
  const int w = blockIdx.x;            // 0..2047
  const int cc0 = blockIdx.y << 5;
  const int b = w >> 8, hb = (w >> 4) & 15, wb = w & 15;
  __shared__ __align__(16) ushort_t tile[64][32];
  const int tid = threadIdx.x;
  const int ci = tid >> 3, row = tid & 7;
  const int c = cc0 + ci;
  const float a = gamma[c] * rsqrtf(var[c] + 1e-5f);
  const float sh = beta[c] - mean[c] * a;
  const float* xp = x + (((size_t)b * 512 + c) * 128 + (hb << 3) + row) * 128 + (wb << 3);
#pragma unroll
  for (int j = 0; j < 8; ++j) tile[(row << 3) + j][ci] = f2bf(xp[j] * a + sh);
  __syncthreads();
  const int n = tid >> 2, d0 = (tid & 3) << 3;
  *(uint4*)(A0 + (size_t)((w << 6) + n) * 512 + cc0 + d0) = *(const uint4*)&tile[n][d0];
}

// ---------------------------------------------------------------------------
// bf16 MFMA GEMM: C[M,N] = A[M,K] @ Bt[N,K]^T + bias  (EPI=1: exact GELU)
// 128x128 tile, BK=32, global_load_lds width-16, 4 waves x 4x4 MFMA frags
// ---------------------------------------------------------------------------
template <int EPI>
__global__ __launch_bounds__(256) void gemm_bt(
    const ushort_t* __restrict__ A, const ushort_t* __restrict__ Bt,
    const float* __restrict__ bias, ushort_t* __restrict__ C,
    int M, int N, int K) {
  __shared__ __align__(16) ushort_t lA[128 * 32];
  __shared__ __align__(16) ushort_t lB[128 * 32];
  const int tid = threadIdx.x;
  const int wave = tid >> 6, lane = tid & 63;
  const int m0 = blockIdx.y << 7, n0 = blockIdx.x << 7;
  const int wm = (wave & 1) << 6, wn = (wave >> 1) << 6;

  float4v acc[4][4];
#pragma unroll
  for (int i = 0; i < 4; ++i)
#pragma unroll
    for (int j = 0; j < 4; ++j)
#pragma unroll
      for (int r = 0; r < 4; ++r) acc[i][j][r] = 0.0f;

  const int srow = (wave << 5) + (lane >> 2);   // staging row within tile
  const int skb = (lane & 3) << 3;              // staging k offset
  const ushort_t* Ag = A + (size_t)(m0 + srow) * K + skb;
  const ushort_t* Bg = Bt + (size_t)(n0 + srow) * K + skb;
  ushort_t* lA0 = &lA[(wave << 5) * 32];
  ushort_t* lA1 = &lA[((wave << 5) + 16) * 32];
  ushort_t* lB0 = &lB[(wave << 5) * 32];
  ushort_t* lB1 = &lB[((wave << 5) + 16) * 32];
  const int fr = lane & 15;
  const int fk = (lane >> 4) << 3;

  for (int kt = 0; kt < K; kt += 32) {
    async16(Ag + kt, lA0);
    async16(Ag + kt + (size_t)16 * K, lA1);
    async16(Bg + kt, lB0);
    async16(Bg + kt + (size_t)16 * K, lB1);
    __syncthreads();
    short8 af[4], bfr[4];
#pragma unroll
    for (int i = 0; i < 4; ++i) {
      af[i] = *(const short8*)&lA[(wm + (i << 4) + fr) * 32 + fk];
      bfr[i] = *(const short8*)&lB[(wn + (i << 4) + fr) * 32 + fk];
    }
#pragma unroll
    for (int i = 0; i < 4; ++i)
#pragma unroll
      for (int j = 0; j < 4; ++j)
        acc[i][j] = __builtin_amdgcn_mfma_f32_16x16x32_bf16(af[i], bfr[j], acc[i][j], 0, 0, 0);
    __syncthreads();
  }

  const int cr = (lane >> 4) << 2;
  const int cc = lane & 15;
#pragma unroll
  for (int j = 0; j < 4; ++j) {
    const int col = n0 + wn + (j << 4) + cc;
    const float bv = bias[col];
#pragma unroll
    for (int i = 0; i < 4; ++i) {
      size_t base = (size_t)(m0 + wm + (i << 4) + cr) * N + col;
#pragma unroll
      for (int r = 0; r < 4; ++r) {
        float v = acc[i][j][r] + bv;
        if (EPI == 1) v = 0.5f * v * (1.0f + erff(v * 0.70710678118654752f));
        C[base + (size_t)r * N] = f2bf(v);
      }
    }
  }
}

// ---------------------------------------------------------------------------
// MFMA attention: one block per (window, head). 4 waves, each owns 16 query
// rows. Q/K fragments straight from global (k-contiguous bf16x8). S=mfma(Q,K),
// wave-parallel softmax (in-register + shfl_xor over 16-lane groups), P staged
// bf16 in per-wave LDS [16][72], V^T staged in LDS [32][72] (conflict-free
// per-row writes, 2-way==free b128 reads), O=mfma(P,Vt).
// ---------------------------------------------------------------------------
__global__ __launch_bounds__(256) void attn_kernel(
    const ushort_t* __restrict__ QKV, const float* __restrict__ table,
    ushort_t* __restrict__ OUT) {
  const int w = blockIdx.x;            // window 0..2047
  const int h = blockIdx.y;            // head 0..15
  __shared__ __align__(16) ushort_t Vt[32][72];      // V^T, pad to 72 (144B rows)
  __shared__ __align__(16) ushort_t Pw[4][16][72];   // per-wave P rows
  __shared__ float bias_s[225];
  const int tid = threadIdx.x;
  const int wave = tid >> 6, lane = tid & 63;
  const int g = lane >> 4, c = lane & 15;

  if (tid < 225) bias_s[tid] = table[tid * 16 + h];

  const ushort_t* base = QKV + (size_t)(w << 6) * 1536 + h * 32;

  // ---- stage V^T: wave handles d-rows [wave*8, wave*8+8) --------------------
  {
    uint4 vv = *(const uint4*)(base + (size_t)lane * 1536 + 1024 + (wave << 3));
    const ushort_t* vp = (const ushort_t*)&vv;
#pragma unroll
    for (int e = 0; e < 8; ++e) Vt[(wave << 3) + e][lane] = vp[e];
  }

  // ---- Q fragment (A-layout) and 4 K fragments (B-layout) from global ------
  short8 qf = *(const short8*)(base + (size_t)((wave << 4) + c) * 1536 + (g << 3));
  short8 kf[4];
#pragma unroll
  for (int j = 0; j < 4; ++j)
    kf[j] = *(const short8*)(base + (size_t)((j << 4) + c) * 1536 + 512 + (g << 3));

  // ---- S = Q K^T : rows [wave*16, wave*16+16), cols 0..63 -------------------
  float4v acc[4];
#pragma unroll
  for (int j = 0; j < 4; ++j) {
#pragma unroll
    for (int r = 0; r < 4; ++r) acc[j][r] = 0.0f;
    acc[j] = __builtin_amdgcn_mfma_f32_16x16x32_bf16(qf, kf[j], acc[j], 0, 0, 0);
  }

  __syncthreads();   // bias_s + Vt ready

  // ---- scale + relative-position bias --------------------------------------
  const int q0 = (wave << 4) + (g << 2);
#pragma unroll
  for (int j = 0; j < 4; ++j) {
    const int k = (j << 4) + c;
    const int r2 = k >> 3, c2 = k & 7;
#pragma unroll
    for (int r = 0; r < 4; ++r) {
      const int q = q0 + r;
      const int idx = ((q >> 3) - r2 + 7) * 15 + ((q & 7) - c2 + 7);
      acc[j][r] = acc[j][r] * 0.17677669529663689f + bias_s[idx];
    }
  }

  // ---- wave-parallel softmax over cols (4 regs x 16 lanes per row) ---------
#pragma unroll
  for (int r = 0; r < 4; ++r) {
    float m = fmaxf(fmaxf(acc[0][r], acc[1][r]), fmaxf(acc[2][r], acc[3][r]));
    m = fmaxf(m, __shfl_xor(m, 1));
    m = fmaxf(m, __shfl_xor(m, 2));
    m = fmaxf(m, __shfl_xor(m, 4));
    m = fmaxf(m, __shfl_xor(m, 8));
    float s = 0.0f;
#pragma unroll
    for (int j = 0; j < 4; ++j) { acc[j][r] = __expf(acc[j][r] - m); s += acc[j][r]; }
    s += __shfl_xor(s, 1);
    s += __shfl_xor(s, 2);
    s += __shfl_xor(s, 4);
    s += __shfl_xor(s, 8);
    const float inv = 1.0f / s;
#pragma unroll
    for (int j = 0; j < 4; ++j)
      Pw[wave][(g << 2) + r][(j << 4) + c] = f2bf(acc[j][r] * inv);
  }

  __syncthreads();   // P writes visible (and in-wave ds ordering)

  // ---- O = P V : out rows 16, cols 32 --------------------------------------
  float4v oacc[2];
#pragma unroll
  for (int j2 = 0; j2 < 2; ++j2)
#pragma unroll
    for (int r = 0; r < 4; ++r) oacc[j2][r] = 0.0f;
#pragma unroll
  for (int ks = 0; ks < 2; ++ks) {
    short8 pa = *(const short8*)&Pw[wave][c][(ks << 5) + (g << 3)];
#pragma unroll
    for (int j2 = 0; j2 < 2; ++j2) {
      short8 vb = *(const short8*)&Vt[(j2 << 4) + c][(ks << 5) + (g << 3)];
      oacc[j2] = __builtin_amdgcn_mfma_f32_16x16x32_bf16(pa, vb, oacc[j2], 0, 0, 0);
    }
  }

  // ---- write O (token-major, col = h*32 + d) -------------------------------
  ushort_t* op = OUT + (size_t)((w << 6) + (wave << 4)) * 512 + h * 32;
#pragma unroll
  for (int j2 = 0; j2 < 2; ++j2)
#pragma unroll
    for (int r = 0; r < 4; ++r)
      op[(size_t)((g << 2) + r) * 512 + (j2 << 4) + c] = f2bf(oacc[j2][r]);
}

// ---------------------------------------------------------------------------
// Scramble gather (torch .view reinterpretation):
// out(b,c,h,w) <- PROJ flat index decomposed from F = c*16384+hb*1024+wb*64+r2*8+c2
// ---------------------------------------------------------------------------
__device__ __forceinline__ size_t scramble_idx(int b, int F) {
  const int hb0 = F >> 19, wb0 = (F >> 15) & 15;
  const int rr = (F >> 12) & 7, ccol = (F >> 9) & 7, ch = F & 511;
  return ((size_t)(b * 256 + hb0 * 16 + wb0) * 64 + rr * 8 + ccol) * 512 + ch;
}

// x1 = x + gather(PROJ); XN2 = bf16(BN2(x1)), token-major
__global__ __launch_bounds__(256) void prep_mlp(
    const float* __restrict__ x, const ushort_t* __restrict__ PROJ,
    const float* __restrict__ gamma, const float* __restrict__ beta,
    const float* __restrict__ mean, const float* __restrict__ var,
    ushort_t* __restrict__ XN2) {
  const int pc = blockIdx.x;           // 64 consecutive spatial positions
  const int cc0 = blockIdx.y << 5;
  const int p0 = pc << 6;
  const int b = p0 >> 14, hh = (p0 >> 7) & 127;
  __shared__ __align__(16) ushort_t tile[64][32];
  const int tid = threadIdx.x;
  const int ci = tid >> 3, wg = (tid & 7) << 3;
  const int c = cc0 + ci;
  const float a = gamma[c] * rsqrtf(var[c] + 1e-5f);
  const float sh = beta[c] - mean[c] * a;
  const int w0 = (p0 & 127) + wg;
  const float* xp = x + (((size_t)b * 512 + c) * 128 + hh) * 128 + w0;
  const int hb = hh >> 3, r2 = hh & 7;
#pragma unroll
  for (int j = 0; j < 8; ++j) {
    const int ww = w0 + j;
    const int F = (c << 14) + (hb << 10) + ((ww >> 3) << 6) + (r2 << 3) + (ww & 7);
    const float x1 = xp[j] + bf2f(PROJ[scramble_idx(b, F)]);
    tile[wg + j][ci] = f2bf(x1 * a + sh);
  }
  __syncthreads();
  const int i2 = tid >> 2, d0 = (tid & 3) << 3;
  *(uint4*)(XN2 + (size_t)(p0 + i2) * 512 + cc0 + d0) = *(const uint4*)&tile[i2][d0];
}

// out = x + gather(PROJ) + H2   (x1 recomputed in fp32, no 256MB x1 buffer)
__global__ __launch_bounds__(256) void final_add(
    const float* __restrict__ x, const ushort_t* __restrict__ PROJ,
    const ushort_t* __restrict__ H2, float* __restrict__ out) {
  const int pc = blockIdx.x, cc0 = blockIdx.y << 5;
  const int p0 = pc << 6;
  const int b = p0 >> 14, hh = (p0 >> 7) & 127;
  __shared__ float tile[32][65];
  const int tid = threadIdx.x;
  {
    const int i2 = tid >> 2, d0 = (tid & 3) << 3;
    const ushort_t* hp = H2 + (size_t)(p0 + i2) * 512 + cc0 + d0;
#pragma unroll
    for (int j = 0; j < 8; ++j) tile[d0 + j][i2] = bf2f(hp[j]);
  }
  __syncthreads();
  const int ci = tid >> 3, wg = (tid & 7) << 3;
  const int c = cc0 + ci;
  const int w0 = (p0 & 127) + wg;
  const float* xp = x + (((size_t)b * 512 + c) * 128 + hh) * 128 + w0;
  float* op = out + (((size_t)b * 512 + c) * 128 + hh) * 128 + w0;
  const int hb = hh >> 3, r2 = hh & 7;
#pragma unroll
  for (int j = 0; j < 8; ++j) {
    const int ww = w0 + j;
    const int F = (c << 14) + (hb << 10) + ((ww >> 3) << 6) + (r2 << 3) + (ww & 7);
    op[j] = xp[j] + bf2f(PROJ[scramble_idx(b, F)]) + tile[ci][wg + j];
  }
}

// ---------------------------------------------------------------------------
extern "C" void kernel_launch(void* const* d_in, const int* in_sizes, int n_in,
                              void* d_out, int out_size, void* d_ws, size_t ws_size,
                              hipStream_t stream) {
  const float* x      = (const float*)d_in[0];
  const float* qkv_w  = (const float*)d_in[1];
  const float* qkv_b  = (const float*)d_in[2];
  const float* proj_w = (const float*)d_in[3];
  const float* proj_b = (const float*)d_in[4];
  const float* rel_t  = (const float*)d_in[5];
  const float* bn1g = (const float*)d_in[6];
  const float* bn1b = (const float*)d_in[7];
  const float* bn1m = (const float*)d_in[8];
  const float* bn1v = (const float*)d_in[9];
  const float* w1 = (const float*)d_in[10];
  const float* b1 = (const float*)d_in[11];
  const float* w2 = (const float*)d_in[12];
  const float* b2 = (const float*)d_in[13];
  const float* bn2g = (const float*)d_in[14];
  const float* bn2b = (const float*)d_in[15];
  const float* bn2m = (const float*)d_in[16];
  const float* bn2v = (const float*)d_in[17];
  float* out = (float*)d_out;

  char* ws = (char*)d_ws;
  const size_t SZ = (size_t)131072 * 512 * 2;           // 128 MB token-major bf16
  ushort_t* WQKV  = (ushort_t*)(ws);                    // 1536x512
  ushort_t* WPROJ = (ushort_t*)(ws + 1572864);          // 512x512
  ushort_t* W1B   = (ushort_t*)(ws + 2097152);
  ushort_t* W2B   = (ushort_t*)(ws + 2621440);
  ushort_t* A0    = (ushort_t*)(ws + 3145728);          // [131072,512]
  ushort_t* QKV   = (ushort_t*)(ws + 3145728 + SZ);     // [131072,1536]
  ushort_t* OUTB  = A0;                                 // attn out (A0 dead)
  ushort_t* PROJ  = QKV;                                // QKV dead after attn
  ushort_t* XN2   = (ushort_t*)((char*)QKV + SZ);
  ushort_t* H1    = (ushort_t*)((char*)QKV + 2 * SZ);
  ushort_t* H2    = A0;                                 // OUTB dead after proj
  // peak ws use: 3145728 + 4*SZ = 540,016,640 bytes

  transpose_cast<<<(512 * 1536 + 255) / 256, 256, 0, stream>>>(qkv_w, WQKV, 512, 1536);
  transpose_cast<<<(512 * 512 + 255) / 256, 256, 0, stream>>>(proj_w, WPROJ, 512, 512);
  cast_bf<<<(512 * 512 + 255) / 256, 256, 0, stream>>>(w1, W1B, 512 * 512);
  cast_bf<<<(512 * 512 + 255) / 256, 256, 0, stream>>>(w2, W2B, 512 * 512);

  prep_qkv<<<dim3(2048, 16), 256, 0, stream>>>(x, bn1g, bn1b, bn1m, bn1v, A0);
  gemm_bt<0><<<dim3(12, 1024), 256, 0, stream>>>(A0, WQKV, qkv_b, QKV, 131072, 1536, 512);
  attn_kernel<<<dim3(2048, 16), 256, 0, stream>>>(QKV, rel_t, OUTB);
  gemm_bt<0><<<dim3(4, 1024), 256, 0, stream>>>(OUTB, WPROJ, proj_b, PROJ, 131072, 512, 512);
  prep_mlp<<<dim3(2048, 16), 256, 0, stream>>>(x, PROJ, bn2g, bn2b, bn2m, bn2v, XN2);
  gemm_bt<1><<<dim3(4, 1024), 256, 0, stream>>>(XN2, W1B, b1, H1, 131072, 512, 512);
  gemm_bt<0><<<dim3(4, 1024), 256, 0, stream>>>(H1, W2B, b2, H2, 131072, 512, 512);
  final_add<<<dim3(2048, 16), 256, 0, stream>>>(x, PROJ, H2, out);
}

// Round 2
// 1749.641 us; speedup vs baseline: 1.2301x; 1.1047x over previous
//
#include <hip/hip_runtime.h>
#include <cstddef>

// ---------------------------------------------------------------------------
// SparseAttnLayer: BN1 -> window QKV GEMM -> 16-head windowed attention
// -> proj GEMM -> scrambled window_reverse residual -> BN2 -> MLP(1x1 convs,
// exact GELU) -> residual.  GEMMs: 256x256 8-phase bf16 MFMA template.
// ---------------------------------------------------------------------------

typedef unsigned short ushort_t;
typedef __attribute__((ext_vector_type(8))) short short8;   // 8 bf16 (4 VGPRs)
typedef __attribute__((ext_vector_type(4))) float float4v;  // MFMA acc

__device__ __forceinline__ float bf2f(unsigned short h) {
  union { unsigned int u; float f; } c; c.u = ((unsigned int)h) << 16; return c.f;
}
__device__ __forceinline__ unsigned short f2bf(float f) {
  union { float f; unsigned int u; } c; c.f = f;
  unsigned int u = c.u;
  unsigned int r = u + 0x7fffu + ((u >> 16) & 1u);   // RNE
  return (unsigned short)(r >> 16);
}
__device__ __forceinline__ void async16(const void* g, void* l) {
  __builtin_amdgcn_global_load_lds(
      (const __attribute__((address_space(1))) unsigned int*)g,
      (__attribute__((address_space(3))) unsigned int*)l, 16, 0, 0);
}

#define BAR() asm volatile("s_barrier" ::: "memory")
#define WAITV6() asm volatile("s_waitcnt vmcnt(6)" ::: "memory")
#define WAITV0() asm volatile("s_waitcnt vmcnt(0)" ::: "memory")

// ---------------------------------------------------------------------------
// Weight prep: Bt[n][k] = W[k][n] (bf16);  plain cast for (o,c)-layout weights
// ---------------------------------------------------------------------------
__global__ void transpose_cast(const float* __restrict__ W, ushort_t* __restrict__ Wt,
                               int K, int N) {
  int idx = blockIdx.x * 256 + threadIdx.x;
  if (idx >= K * N) return;
  int nn = idx / K, kk = idx - nn * K;
  Wt[idx] = f2bf(W[(size_t)kk * N + nn]);
}
__global__ void cast_bf(const float* __restrict__ W, ushort_t* __restrict__ Wt, int total) {
  int idx = blockIdx.x * 256 + threadIdx.x;
  if (idx < total) Wt[idx] = f2bf(W[idx]);
}

// ---------------------------------------------------------------------------
// BN1 + window partition + bf16 cast: A0[(win*64+n)][c]
// ---------------------------------------------------------------------------
__global__ __launch_bounds__(256) void prep_qkv(
    const float* __restrict__ x, const float* __restrict__ gamma,
    const float* __restrict__ beta, const float* __restrict__ mean,
    const float* __restrict__ var, ushort_t* __restrict__ A0) {
  const int w = blockIdx.x;            // 0..2047
  const int cc0 = blockIdx.y << 5;
  const int b = w >> 8, hb = (w >> 4) & 15, wb = w & 15;
  __shared__ __align__(16) ushort_t tile[64][32];
  const int tid = threadIdx.x;
  const int ci = tid >> 3, row = tid & 7;
  const int c = cc0 + ci;
  const float a = gamma[c] * rsqrtf(var[c] + 1e-5f);
  const float sh = beta[c] - mean[c] * a;
  const float* xp = x + (((size_t)b * 512 + c) * 128 + (hb << 3) + row) * 128 + (wb << 3);
#pragma unroll
  for (int j = 0; j < 8; ++j) tile[(row << 3) + j][ci] = f2bf(xp[j] * a + sh);
  __syncthreads();
  const int n = tid >> 2, d0 = (tid & 3) << 3;
  *(uint4*)(A0 + (size_t)((w << 6) + n) * 512 + cc0 + d0) = *(const uint4*)&tile[n][d0];
}

// ---------------------------------------------------------------------------
// 256x256 8-phase bf16 MFMA GEMM (T2 swizzle + T3/T4 counted vmcnt + T5).
// C[M,N] = A[M,K] @ Bt[N,K]^T + bias.  EPI=1: exact GELU.
// 8 waves (2Mx4N), per-wave 128x64 out, BK=64, 2 K-tiles / 8 phases per iter.
// LDS 128 KiB: buf{0,1} x (A[256][64], B[256][64]) bf16, rows 128 B,
// XOR-swizzled seg ^= row&7 (both-sides: pre-swizzled global src, swz read).
// Stripe staging map (phase -> region, proven dead 1 phase earlier):
//   P1:B1.n0<-kt1  P2:A0.m0<-kt+2  P3:B0.n1  P4:A0.m1 [vmcnt6]
//   P5:B0.n0       P6:A1.m0<-kt+3  P7:B1.n1  P8:A1.m1 [vmcnt6]
// ---------------------------------------------------------------------------
#define QUAD(BB, MH, NH)                                                        \
  __builtin_amdgcn_s_setprio(1);                                                \
  _Pragma("unroll")                                                             \
  for (int mi = 0; mi < 4; ++mi) {                                              \
    _Pragma("unroll")                                                           \
    for (int nj = 0; nj < 2; ++nj) {                                            \
      _Pragma("unroll")                                                         \
      for (int kk = 0; kk < 2; ++kk)                                            \
        acc[(MH * 4) + mi][(NH * 2) + nj] =                                     \
            __builtin_amdgcn_mfma_f32_16x16x32_bf16(                            \
                a[mi][kk], BB[nj][kk], acc[(MH * 4) + mi][(NH * 2) + nj], 0, 0, 0); \
    }                                                                           \
  }                                                                             \
  __builtin_amdgcn_s_setprio(0);

template <int EPI>
__global__ __launch_bounds__(512, 2) void gemm256(
    const ushort_t* __restrict__ A, const ushort_t* __restrict__ Bt,
    const float* __restrict__ bias, ushort_t* __restrict__ C,
    int M, int N, int K) {
  __shared__ __align__(16) ushort_t smem[65536];   // 128 KiB
  ushort_t* A0L = smem;                 // buf0 A: [256][64]
  ushort_t* B0L = smem + 16384;         // buf0 B: [256][64]
  ushort_t* A1L = smem + 32768;
  ushort_t* B1L = smem + 49152;

  const int tid = threadIdx.x;
  const int wid = tid >> 6, lane = tid & 63;

  // bijective XCD swizzle (m204): consecutive work-ids -> same XCD chunk
  const int gx = gridDim.x;
  const int nwg = gx * gridDim.y;
  const int orig = blockIdx.y * gx + blockIdx.x;
  const int q = nwg >> 3, r = nwg & 7;
  const int xcd = orig & 7, lid = orig >> 3;
  const int swz = (xcd < r ? xcd * (q + 1) : r * (q + 1) + (xcd - r) * q) + lid;
  const int by = swz / gx, bx = swz - by * gx;
  const int m0 = by << 8, n0 = bx << 8;

  const int NT = K >> 6;        // 64-wide K-tiles (8 for K=512)
  const int NI = NT >> 1;

  // staging source precompute (dest linear, src seg pre-swizzled: seg^row&7)
  const int sseg = (lane & 7) ^ (lane >> 3);     // (lane>>3) == destrow&7
  auto stA = [&](ushort_t* dst, int stripe, int kt) {
#pragma unroll
    for (int j = 0; j < 2; ++j) {
      const int pr = (j << 7) + (stripe << 6) + (wid << 3);   // wave-uniform row base
      async16(A + (size_t)(m0 + pr + (lane >> 3)) * K + (kt << 6) + (sseg << 3),
              dst + ((size_t)pr << 6));
    }
  };
  auto stB = [&](ushort_t* dst, int stripe, int kt) {
#pragma unroll
    for (int j = 0; j < 2; ++j) {
      const int pr = (j << 7) + ((wid >> 2) << 6) + (stripe << 5) + ((wid & 3) << 3);
      async16(Bt + (size_t)(n0 + pr + (lane >> 3)) * K + (kt << 6) + (sseg << 3),
              dst + ((size_t)pr << 6));
    }
  };

  // fragment addressing (swizzled read: seg ^ (row&7))
  const int fr = lane & 15, kg = lane >> 4;
  const int wr = wid >> 2, wc = wid & 3;
  const int ar0 = (wr << 7) + fr;        // + mi*16
  const int br0 = (wc << 6) + fr;        // + ni*16
  const int sx = fr & 7;
  auto ldA = [&](const ushort_t* buf, int mi_abs, int kk) -> short8 {
    const int row = ar0 + (mi_abs << 4);
    const int seg = ((kk << 2) + kg) ^ sx;
    return *(const short8*)(buf + (row << 6) + (seg << 3));
  };
  auto ldB = [&](const ushort_t* buf, int ni_abs, int kk) -> short8 {
    const int row = br0 + (ni_abs << 4);
    const int seg = ((kk << 2) + kg) ^ sx;
    return *(const short8*)(buf + (row << 6) + (seg << 3));
  };

  short8 a[4][2], b0[2][2], b1[2][2];
  float4v acc[8][4];
#pragma unroll
  for (int i = 0; i < 8; ++i)
#pragma unroll
    for (int j = 0; j < 4; ++j)
#pragma unroll
      for (int rr = 0; rr < 4; ++rr) acc[i][j][rr] = 0.0f;

  // ---- prologue: buf0 fully + buf1 {A.m0, B.n1, A.m1}; B1.n0 staged at P1 --
  stA(A0L, 0, 0);
  stB(B0L, 0, 0);
  stB(B0L, 1, 0);
  stA(A0L, 1, 0);
  stA(A1L, 0, 1);
  stB(B1L, 1, 1);
  stA(A1L, 1, 1);
  WAITV6();            // first 8 (all of buf0) landed
  BAR();

  for (int i = 0; i < NI; ++i) {
    const int ktB = 2 * i + 1;
    const int kt2 = 2 * i + 2, kt3 = 2 * i + 3;
    const bool st = (kt2 < NT);
    // ---- P1: buf0 quad(0,0) ------------------------------------------------
#pragma unroll
    for (int mi = 0; mi < 4; ++mi) { a[mi][0] = ldA(A0L, mi, 0); a[mi][1] = ldA(A0L, mi, 1); }
#pragma unroll
    for (int nj = 0; nj < 2; ++nj) { b0[nj][0] = ldB(B0L, nj, 0); b0[nj][1] = ldB(B0L, nj, 1); }
    stB(B1L, 0, ktB);
    BAR();
    QUAD(b0, 0, 0);
    BAR();
    // ---- P2: buf0 quad(0,1) ------------------------------------------------
#pragma unroll
    for (int nj = 0; nj < 2; ++nj) { b1[nj][0] = ldB(B0L, 2 + nj, 0); b1[nj][1] = ldB(B0L, 2 + nj, 1); }
    if (st) stA(A0L, 0, kt2);
    BAR();
    QUAD(b1, 0, 1);
    BAR();
    // ---- P3: buf0 quad(1,1) ------------------------------------------------
#pragma unroll
    for (int mi = 0; mi < 4; ++mi) { a[mi][0] = ldA(A0L, 4 + mi, 0); a[mi][1] = ldA(A0L, 4 + mi, 1); }
    if (st) stB(B0L, 1, kt2);
    BAR();
    QUAD(b1, 1, 1);
    BAR();
    // ---- P4: buf0 quad(1,0); counted vmcnt ---------------------------------
    if (st) stA(A0L, 1, kt2);
    BAR();
    QUAD(b0, 1, 0);
    if (st) { WAITV6(); } else { WAITV0(); }
    BAR();
    // ---- P5: buf1 quad(0,0) ------------------------------------------------
#pragma unroll
    for (int mi = 0; mi < 4; ++mi) { a[mi][0] = ldA(A1L, mi, 0); a[mi][1] = ldA(A1L, mi, 1); }
#pragma unroll
    for (int nj = 0; nj < 2; ++nj) { b0[nj][0] = ldB(B1L, nj, 0); b0[nj][1] = ldB(B1L, nj, 1); }
    if (st) stB(B0L, 0, kt2);
    BAR();
    QUAD(b0, 0, 0);
    BAR();
    // ---- P6: buf1 quad(0,1) ------------------------------------------------
#pragma unroll
    for (int nj = 0; nj < 2; ++nj) { b1[nj][0] = ldB(B1L, 2 + nj, 0); b1[nj][1] = ldB(B1L, 2 + nj, 1); }
    if (st) stA(A1L, 0, kt3);
    BAR();
    QUAD(b1, 0, 1);
    BAR();
    // ---- P7: buf1 quad(1,1) ------------------------------------------------
#pragma unroll
    for (int mi = 0; mi < 4; ++mi) { a[mi][0] = ldA(A1L, 4 + mi, 0); a[mi][1] = ldA(A1L, 4 + mi, 1); }
    if (st) stB(B1L, 1, kt3);
    BAR();
    QUAD(b1, 1, 1);
    BAR();
    // ---- P8: buf1 quad(1,0); counted vmcnt ---------------------------------
    if (st) stA(A1L, 1, kt3);
    BAR();
    QUAD(b0, 1, 0);
    if (st) { WAITV6(); }
    BAR();
  }

  // ---- epilogue: bias (+GELU) + bf16 store ---------------------------------
  const int cr = kg << 2;
#pragma unroll
  for (int ni = 0; ni < 4; ++ni) {
    const int col = n0 + (wc << 6) + (ni << 4) + fr;
    const float bv = bias[col];
#pragma unroll
    for (int mi = 0; mi < 8; ++mi) {
      const size_t base = (size_t)(m0 + (wr << 7) + (mi << 4) + cr) * N + col;
#pragma unroll
      for (int rr = 0; rr < 4; ++rr) {
        float v = acc[mi][ni][rr] + bv;
        if (EPI == 1) v = 0.5f * v * (1.0f + erff(v * 0.70710678118654752f));
        C[base + (size_t)rr * N] = f2bf(v);
      }
    }
  }
}

// ---------------------------------------------------------------------------
// MFMA attention: one block per (window, head). 4 waves x 16 query rows.
// ---------------------------------------------------------------------------
__global__ __launch_bounds__(256) void attn_kernel(
    const ushort_t* __restrict__ QKV, const float* __restrict__ table,
    ushort_t* __restrict__ OUT) {
  const int w = blockIdx.x;            // window 0..2047
  const int h = blockIdx.y;            // head 0..15
  __shared__ __align__(16) ushort_t Vt[32][72];      // V^T, pad to 72 (144B rows)
  __shared__ __align__(16) ushort_t Pw[4][16][72];   // per-wave P rows
  __shared__ float bias_s[225];
  const int tid = threadIdx.x;
  const int wave = tid >> 6, lane = tid & 63;
  const int g = lane >> 4, c = lane & 15;

  if (tid < 225) bias_s[tid] = table[tid * 16 + h];

  const ushort_t* base = QKV + (size_t)(w << 6) * 1536 + h * 32;

  // ---- stage V^T: wave handles d-rows [wave*8, wave*8+8) --------------------
  {
    uint4 vv = *(const uint4*)(base + (size_t)lane * 1536 + 1024 + (wave << 3));
    const ushort_t* vp = (const ushort_t*)&vv;
#pragma unroll
    for (int e = 0; e < 8; ++e) Vt[(wave << 3) + e][lane] = vp[e];
  }

  // ---- Q fragment (A-layout) and 4 K fragments (B-layout) from global ------
  short8 qf = *(const short8*)(base + (size_t)((wave << 4) + c) * 1536 + (g << 3));
  short8 kf[4];
#pragma unroll
  for (int j = 0; j < 4; ++j)
    kf[j] = *(const short8*)(base + (size_t)((j << 4) + c) * 1536 + 512 + (g << 3));

  // ---- S = Q K^T -----------------------------------------------------------
  float4v acc[4];
#pragma unroll
  for (int j = 0; j < 4; ++j) {
#pragma unroll
    for (int r = 0; r < 4; ++r) acc[j][r] = 0.0f;
    acc[j] = __builtin_amdgcn_mfma_f32_16x16x32_bf16(qf, kf[j], acc[j], 0, 0, 0);
  }

  __syncthreads();   // bias_s + Vt ready

  // ---- scale + relative-position bias --------------------------------------
  const int q0 = (wave << 4) + (g << 2);
#pragma unroll
  for (int j = 0; j < 4; ++j) {
    const int k = (j << 4) + c;
    const int r2 = k >> 3, c2 = k & 7;
#pragma unroll
    for (int r = 0; r < 4; ++r) {
      const int qq = q0 + r;
      const int idx = ((qq >> 3) - r2 + 7) * 15 + ((qq & 7) - c2 + 7);
      acc[j][r] = acc[j][r] * 0.17677669529663689f + bias_s[idx];
    }
  }

  // ---- wave-parallel softmax over cols -------------------------------------
#pragma unroll
  for (int r = 0; r < 4; ++r) {
    float m = fmaxf(fmaxf(acc[0][r], acc[1][r]), fmaxf(acc[2][r], acc[3][r]));
    m = fmaxf(m, __shfl_xor(m, 1));
    m = fmaxf(m, __shfl_xor(m, 2));
    m = fmaxf(m, __shfl_xor(m, 4));
    m = fmaxf(m, __shfl_xor(m, 8));
    float s = 0.0f;
#pragma unroll
    for (int j = 0; j < 4; ++j) { acc[j][r] = __expf(acc[j][r] - m); s += acc[j][r]; }
    s += __shfl_xor(s, 1);
    s += __shfl_xor(s, 2);
    s += __shfl_xor(s, 4);
    s += __shfl_xor(s, 8);
    const float inv = 1.0f / s;
#pragma unroll
    for (int j = 0; j < 4; ++j)
      Pw[wave][(g << 2) + r][(j << 4) + c] = f2bf(acc[j][r] * inv);
  }

  __syncthreads();   // P writes visible

  // ---- O = P V -------------------------------------------------------------
  float4v oacc[2];
#pragma unroll
  for (int j2 = 0; j2 < 2; ++j2)
#pragma unroll
    for (int r = 0; r < 4; ++r) oacc[j2][r] = 0.0f;
#pragma unroll
  for (int ks = 0; ks < 2; ++ks) {
    short8 pa = *(const short8*)&Pw[wave][c][(ks << 5) + (g << 3)];
#pragma unroll
    for (int j2 = 0; j2 < 2; ++j2) {
      short8 vb = *(const short8*)&Vt[(j2 << 4) + c][(ks << 5) + (g << 3)];
      oacc[j2] = __builtin_amdgcn_mfma_f32_16x16x32_bf16(pa, vb, oacc[j2], 0, 0, 0);
    }
  }

  // ---- write O (token-major, col = h*32 + d) -------------------------------
  ushort_t* op = OUT + (size_t)((w << 6) + (wave << 4)) * 512 + h * 32;
#pragma unroll
  for (int j2 = 0; j2 < 2; ++j2)
#pragma unroll
    for (int r = 0; r < 4; ++r)
      op[(size_t)((g << 2) + r) * 512 + (j2 << 4) + c] = f2bf(oacc[j2][r]);
}

// ---------------------------------------------------------------------------
// Scramble gather (torch .view reinterpretation)
// ---------------------------------------------------------------------------
__device__ __forceinline__ size_t scramble_idx(int b, int F) {
  const int hb0 = F >> 19, wb0 = (F >> 15) & 15;
  const int rr = (F >> 12) & 7, ccol = (F >> 9) & 7, ch = F & 511;
  return ((size_t)(b * 256 + hb0 * 16 + wb0) * 64 + rr * 8 + ccol) * 512 + ch;
}

// x1 = x + gather(PROJ); XN2 = bf16(BN2(x1)), token-major
__global__ __launch_bounds__(256) void prep_mlp(
    const float* __restrict__ x, const ushort_t* __restrict__ PROJ,
    const float* __restrict__ gamma, const float* __restrict__ beta,
    const float* __restrict__ mean, const float* __restrict__ var,
    ushort_t* __restrict__ XN2) {
  const int pc = blockIdx.x;           // 64 consecutive spatial positions
  const int cc0 = blockIdx.y << 5;
  const int p0 = pc << 6;
  const int b = p0 >> 14, hh = (p0 >> 7) & 127;
  __shared__ __align__(16) ushort_t tile[64][32];
  const int tid = threadIdx.x;
  const int ci = tid >> 3, wg = (tid & 7) << 3;
  const int c = cc0 + ci;
  const float a = gamma[c] * rsqrtf(var[c] + 1e-5f);
  const float sh = beta[c] - mean[c] * a;
  const int w0 = (p0 & 127) + wg;
  const float* xp = x + (((size_t)b * 512 + c) * 128 + hh) * 128 + w0;
  const int hb = hh >> 3, r2 = hh & 7;
#pragma unroll
  for (int j = 0; j < 8; ++j) {
    const int ww = w0 + j;
    const int F = (c << 14) + (hb << 10) + ((ww >> 3) << 6) + (r2 << 3) + (ww & 7);
    const float x1 = xp[j] + bf2f(PROJ[scramble_idx(b, F)]);
    tile[wg + j][ci] = f2bf(x1 * a + sh);
  }
  __syncthreads();
  const int i2 = tid >> 2, d0 = (tid & 3) << 3;
  *(uint4*)(XN2 + (size_t)(p0 + i2) * 512 + cc0 + d0) = *(const uint4*)&tile[i2][d0];
}

// out = x + gather(PROJ) + H2
__global__ __launch_bounds__(256) void final_add(
    const float* __restrict__ x, const ushort_t* __restrict__ PROJ,
    const ushort_t* __restrict__ H2, float* __restrict__ out) {
  const int pc = blockIdx.x, cc0 = blockIdx.y << 5;
  const int p0 = pc << 6;
  const int b = p0 >> 14, hh = (p0 >> 7) & 127;
  __shared__ float tile[32][65];
  const int tid = threadIdx.x;
  {
    const int i2 = tid >> 2, d0 = (tid & 3) << 3;
    const ushort_t* hp = H2 + (size_t)(p0 + i2) * 512 + cc0 + d0;
#pragma unroll
    for (int j = 0; j < 8; ++j) tile[d0 + j][i2] = bf2f(hp[j]);
  }
  __syncthreads();
  const int ci = tid >> 3, wg = (tid & 7) << 3;
  const int c = cc0 + ci;
  const int w0 = (p0 & 127) + wg;
  const float* xp = x + (((size_t)b * 512 + c) * 128 + hh) * 128 + w0;
  float* op = out + (((size_t)b * 512 + c) * 128 + hh) * 128 + w0;
  const int hb = hh >> 3, r2 = hh & 7;
#pragma unroll
  for (int j = 0; j < 8; ++j) {
    const int ww = w0 + j;
    const int F = (c << 14) + (hb << 10) + ((ww >> 3) << 6) + (r2 << 3) + (ww & 7);
    op[j] = xp[j] + bf2f(PROJ[scramble_idx(b, F)]) + tile[ci][wg + j];
  }
}

// ---------------------------------------------------------------------------
extern "C" void kernel_launch(void* const* d_in, const int* in_sizes, int n_in,
                              void* d_out, int out_size, void* d_ws, size_t ws_size,
                              hipStream_t stream) {
  const float* x      = (const float*)d_in[0];
  const float* qkv_w  = (const float*)d_in[1];
  const float* qkv_b  = (const float*)d_in[2];
  const float* proj_w = (const float*)d_in[3];
  const float* proj_b = (const float*)d_in[4];
  const float* rel_t  = (const float*)d_in[5];
  const float* bn1g = (const float*)d_in[6];
  const float* bn1b = (const float*)d_in[7];
  const float* bn1m = (const float*)d_in[8];
  const float* bn1v = (const float*)d_in[9];
  const float* w1 = (const float*)d_in[10];
  const float* b1 = (const float*)d_in[11];
  const float* w2 = (const float*)d_in[12];
  const float* b2 = (const float*)d_in[13];
  const float* bn2g = (const float*)d_in[14];
  const float* bn2b = (const float*)d_in[15];
  const float* bn2m = (const float*)d_in[16];
  const float* bn2v = (const float*)d_in[17];
  float* out = (float*)d_out;

  char* ws = (char*)d_ws;
  const size_t SZ = (size_t)131072 * 512 * 2;           // 128 MB token-major bf16
  ushort_t* WQKV  = (ushort_t*)(ws);                    // 1536x512
  ushort_t* WPROJ = (ushort_t*)(ws + 1572864);          // 512x512
  ushort_t* W1B   = (ushort_t*)(ws + 2097152);
  ushort_t* W2B   = (ushort_t*)(ws + 2621440);
  ushort_t* A0    = (ushort_t*)(ws + 3145728);          // [131072,512]
  ushort_t* QKV   = (ushort_t*)(ws + 3145728 + SZ);     // [131072,1536]
  ushort_t* OUTB  = A0;                                 // attn out (A0 dead)
  ushort_t* PROJ  = QKV;                                // QKV dead after attn
  ushort_t* XN2   = (ushort_t*)((char*)QKV + SZ);
  ushort_t* H1    = (ushort_t*)((char*)QKV + 2 * SZ);
  ushort_t* H2    = A0;                                 // OUTB dead after proj
  // peak ws use: 3145728 + 4*SZ = 540,016,640 bytes

  transpose_cast<<<(512 * 1536 + 255) / 256, 256, 0, stream>>>(qkv_w, WQKV, 512, 1536);
  transpose_cast<<<(512 * 512 + 255) / 256, 256, 0, stream>>>(proj_w, WPROJ, 512, 512);
  cast_bf<<<(512 * 512 + 255) / 256, 256, 0, stream>>>(w1, W1B, 512 * 512);
  cast_bf<<<(512 * 512 + 255) / 256, 256, 0, stream>>>(w2, W2B, 512 * 512);

  prep_qkv<<<dim3(2048, 16), 256, 0, stream>>>(x, bn1g, bn1b, bn1m, bn1v, A0);
  gemm256<0><<<dim3(6, 512), 512, 0, stream>>>(A0, WQKV, qkv_b, QKV, 131072, 1536, 512);
  attn_kernel<<<dim3(2048, 16), 256, 0, stream>>>(QKV, rel_t, OUTB);
  gemm256<0><<<dim3(2, 512), 512, 0, stream>>>(OUTB, WPROJ, proj_b, PROJ, 131072, 512, 512);
  prep_mlp<<<dim3(2048, 16), 256, 0, stream>>>(x, PROJ, bn2g, bn2b, bn2m, bn2v, XN2);
  gemm256<1><<<dim3(2, 512), 512, 0, stream>>>(XN2, W1B, b1, H1, 131072, 512, 512);
  gemm256<0><<<dim3(2, 512), 512, 0, stream>>>(H1, W2B, b2, H2, 131072, 512, 512);
  final_add<<<dim3(2048, 16), 256, 0, stream>>>(x, PROJ, H2, out);
}

// Round 3
// 1707.070 us; speedup vs baseline: 1.2608x; 1.0249x over previous
//
#include <hip/hip_runtime.h>
#include <cstddef>

// ---------------------------------------------------------------------------
// SparseAttnLayer: BN1 -> window QKV GEMM -> 16-head windowed attention
// -> proj GEMM (epilogue writes window-reverse-scrambled (B,C,H,W) layout)
// -> BN2 -> MLP(1x1 convs, exact GELU) -> residual.
// GEMMs: 256x256 8-phase bf16 MFMA template (T2 swizzle, counted vmcnt, T5).
// ---------------------------------------------------------------------------

typedef unsigned short ushort_t;
typedef __attribute__((ext_vector_type(8))) short short8;   // 8 bf16 (4 VGPRs)
typedef __attribute__((ext_vector_type(4))) float float4v;  // MFMA acc

__device__ __forceinline__ float bf2f(unsigned short h) {
  union { unsigned int u; float f; } c; c.u = ((unsigned int)h) << 16; return c.f;
}
__device__ __forceinline__ unsigned short f2bf(float f) {
  union { float f; unsigned int u; } c; c.f = f;
  unsigned int u = c.u;
  unsigned int r = u + 0x7fffu + ((u >> 16) & 1u);   // RNE
  return (unsigned short)(r >> 16);
}
__device__ __forceinline__ void async16(const void* g, void* l) {
  __builtin_amdgcn_global_load_lds(
      (const __attribute__((address_space(1))) unsigned int*)g,
      (__attribute__((address_space(3))) unsigned int*)l, 16, 0, 0);
}

#define BAR() asm volatile("s_barrier" ::: "memory")
#define WAITV6() asm volatile("s_waitcnt vmcnt(6)" ::: "memory")
#define WAITV0() asm volatile("s_waitcnt vmcnt(0)" ::: "memory")

// ---------------------------------------------------------------------------
// Weight prep: Bt[n][k] = W[k][n] (bf16);  plain cast for (o,c)-layout weights
// ---------------------------------------------------------------------------
__global__ void transpose_cast(const float* __restrict__ W, ushort_t* __restrict__ Wt,
                               int K, int N) {
  int idx = blockIdx.x * 256 + threadIdx.x;
  if (idx >= K * N) return;
  int nn = idx / K, kk = idx - nn * K;
  Wt[idx] = f2bf(W[(size_t)kk * N + nn]);
}
__global__ void cast_bf(const float* __restrict__ W, ushort_t* __restrict__ Wt, int total) {
  int idx = blockIdx.x * 256 + threadIdx.x;
  if (idx < total) Wt[idx] = f2bf(W[idx]);
}

// ---------------------------------------------------------------------------
// BN1 + window partition + bf16 cast: A0[(win*64+n)][c]
// ---------------------------------------------------------------------------
__global__ __launch_bounds__(256) void prep_qkv(
    const float* __restrict__ x, const float* __restrict__ gamma,
    const float* __restrict__ beta, const float* __restrict__ mean,
    const float* __restrict__ var, ushort_t* __restrict__ A0) {
  const int w = blockIdx.x;            // 0..2047
  const int cc0 = blockIdx.y << 5;
  const int b = w >> 8, hb = (w >> 4) & 15, wb = w & 15;
  __shared__ __align__(16) ushort_t tile[64][32];
  const int tid = threadIdx.x;
  const int ci = tid >> 3, row = tid & 7;
  const int c = cc0 + ci;
  const float a = gamma[c] * rsqrtf(var[c] + 1e-5f);
  const float sh = beta[c] - mean[c] * a;
  const float* xp = x + (((size_t)b * 512 + c) * 128 + (hb << 3) + row) * 128 + (wb << 3);
#pragma unroll
  for (int j = 0; j < 8; ++j) tile[(row << 3) + j][ci] = f2bf(xp[j] * a + sh);
  __syncthreads();
  const int n = tid >> 2, d0 = (tid & 3) << 3;
  *(uint4*)(A0 + (size_t)((w << 6) + n) * 512 + cc0 + d0) = *(const uint4*)&tile[n][d0];
}

// ---------------------------------------------------------------------------
// 256x256 8-phase bf16 MFMA GEMM.  C[M,N] = A[M,K] @ Bt[N,K]^T + bias.
// EPI=0: plain store (token-major).  EPI=1: exact GELU, token-major.
// EPI=2: window-reverse scramble store into (B,C,H,W) bf16 (proj GEMM):
//   row m = b*16384 + t'; col = ch;  c = t'[13:6]<<1 | t'[5],
//   h = t'[4:1]<<3 | ch[5:3],  w = t'[0]<<6 | ch[8:6]<<3 | ch[2:0].
// 8 waves (2Mx4N), per-wave 128x64 out, BK=64, 2 K-tiles / 8 phases per iter.
// LDS 128 KiB, rows 128 B, XOR-swizzle seg^=row&7 (both-sides, rule 21).
// ---------------------------------------------------------------------------
#define QUAD(BB, MH, NH)                                                        \
  __builtin_amdgcn_s_setprio(1);                                                \
  _Pragma("unroll")                                                             \
  for (int mi = 0; mi < 4; ++mi) {                                              \
    _Pragma("unroll")                                                           \
    for (int nj = 0; nj < 2; ++nj) {                                            \
      _Pragma("unroll")                                                         \
      for (int kk = 0; kk < 2; ++kk)                                            \
        acc[(MH * 4) + mi][(NH * 2) + nj] =                                     \
            __builtin_amdgcn_mfma_f32_16x16x32_bf16(                            \
                a[mi][kk], BB[nj][kk], acc[(MH * 4) + mi][(NH * 2) + nj], 0, 0, 0); \
    }                                                                           \
  }                                                                             \
  __builtin_amdgcn_s_setprio(0);

template <int EPI>
__global__ __launch_bounds__(512, 2) void gemm256(
    const ushort_t* __restrict__ A, const ushort_t* __restrict__ Bt,
    const float* __restrict__ bias, ushort_t* __restrict__ C,
    int M, int N, int K) {
  __shared__ __align__(16) ushort_t smem[65536];   // 128 KiB
  ushort_t* A0L = smem;                 // buf0 A: [256][64]
  ushort_t* B0L = smem + 16384;         // buf0 B: [256][64]
  ushort_t* A1L = smem + 32768;
  ushort_t* B1L = smem + 49152;

  const int tid = threadIdx.x;
  const int wid = tid >> 6, lane = tid & 63;

  // bijective XCD swizzle (m204): consecutive WORK-ids land on one XCD
  const int gx = gridDim.x;
  const int nwg = gx * gridDim.y;
  const int orig = blockIdx.y * gx + blockIdx.x;
  const int q = nwg >> 3, r = nwg & 7;
  const int xcd = orig & 7, lid = orig >> 3;
  const int swz = (xcd < r ? xcd * (q + 1) : r * (q + 1) + (xcd - r) * q) + lid;
  const int by = swz / gx, bx = swz - by * gx;
  const int m0 = by << 8, n0 = bx << 8;

  const int NT = K >> 6;        // 64-wide K-tiles (8 for K=512)
  const int NI = NT >> 1;

  // staging: dest linear, src seg pre-swizzled (seg ^ destrow&7).
  // per-lane global bases hoisted; per-call offset is wave-uniform (SGPR).
  const int sseg = (lane & 7) ^ (lane >> 3);
  const ushort_t* Agl = A + (size_t)(m0 + (lane >> 3)) * K + (sseg << 3);
  const ushort_t* Bgl = Bt + (size_t)(n0 + (lane >> 3)) * K + (sseg << 3);
  auto stA = [&](ushort_t* dst, int stripe, int kt) {
#pragma unroll
    for (int j = 0; j < 2; ++j) {
      const int pr = (j << 7) + (stripe << 6) + (wid << 3);   // wave-uniform
      async16(Agl + pr * K + (kt << 6), dst + (pr << 6));
    }
  };
  auto stB = [&](ushort_t* dst, int stripe, int kt) {
#pragma unroll
    for (int j = 0; j < 2; ++j) {
      const int pr = (j << 7) + ((wid >> 2) << 6) + (stripe << 5) + ((wid & 3) << 3);
      async16(Bgl + pr * K + (kt << 6), dst + (pr << 6));
    }
  };

  // fragment addressing (swizzled read: seg ^ (row&7))
  const int fr = lane & 15, kg = lane >> 4;
  const int wr = wid >> 2, wc = wid & 3;
  const int ar0 = (wr << 7) + fr;        // + mi*16
  const int br0 = (wc << 6) + fr;        // + ni*16
  const int sx = fr & 7;
  auto ldA = [&](const ushort_t* buf, int mi_abs, int kk) -> short8 {
    const int row = ar0 + (mi_abs << 4);
    const int seg = ((kk << 2) + kg) ^ sx;
    return *(const short8*)(buf + (row << 6) + (seg << 3));
  };
  auto ldB = [&](const ushort_t* buf, int ni_abs, int kk) -> short8 {
    const int row = br0 + (ni_abs << 4);
    const int seg = ((kk << 2) + kg) ^ sx;
    return *(const short8*)(buf + (row << 6) + (seg << 3));
  };

  short8 a[4][2], b0[2][2], b1[2][2];
  float4v acc[8][4];
#pragma unroll
  for (int i = 0; i < 8; ++i)
#pragma unroll
    for (int j = 0; j < 4; ++j)
#pragma unroll
      for (int rr = 0; rr < 4; ++rr) acc[i][j][rr] = 0.0f;

  // ---- prologue: buf0 fully + buf1 {A.m0, B.n1, A.m1}; B1.n0 staged at P1 --
  stA(A0L, 0, 0);
  stB(B0L, 0, 0);
  stB(B0L, 1, 0);
  stA(A0L, 1, 0);
  stA(A1L, 0, 1);
  stB(B1L, 1, 1);
  stA(A1L, 1, 1);
  WAITV6();            // first 8 (all of buf0) landed
  BAR();

  for (int i = 0; i < NI; ++i) {
    const int ktB = 2 * i + 1;
    const int kt2 = 2 * i + 2, kt3 = 2 * i + 3;
    const bool st = (kt2 < NT);
    // ---- P1: buf0 quad(0,0) ------------------------------------------------
#pragma unroll
    for (int mi = 0; mi < 4; ++mi) { a[mi][0] = ldA(A0L, mi, 0); a[mi][1] = ldA(A0L, mi, 1); }
#pragma unroll
    for (int nj = 0; nj < 2; ++nj) { b0[nj][0] = ldB(B0L, nj, 0); b0[nj][1] = ldB(B0L, nj, 1); }
    stB(B1L, 0, ktB);
    BAR();
    QUAD(b0, 0, 0);
    BAR();
    // ---- P2: buf0 quad(0,1) ------------------------------------------------
#pragma unroll
    for (int nj = 0; nj < 2; ++nj) { b1[nj][0] = ldB(B0L, 2 + nj, 0); b1[nj][1] = ldB(B0L, 2 + nj, 1); }
    if (st) stA(A0L, 0, kt2);
    BAR();
    QUAD(b1, 0, 1);
    BAR();
    // ---- P3: buf0 quad(1,1) ------------------------------------------------
#pragma unroll
    for (int mi = 0; mi < 4; ++mi) { a[mi][0] = ldA(A0L, 4 + mi, 0); a[mi][1] = ldA(A0L, 4 + mi, 1); }
    if (st) stB(B0L, 1, kt2);
    BAR();
    QUAD(b1, 1, 1);
    BAR();
    // ---- P4: buf0 quad(1,0); counted vmcnt ---------------------------------
    if (st) stA(A0L, 1, kt2);
    BAR();
    QUAD(b0, 1, 0);
    if (st) { WAITV6(); } else { WAITV0(); }
    BAR();
    // ---- P5: buf1 quad(0,0) ------------------------------------------------
#pragma unroll
    for (int mi = 0; mi < 4; ++mi) { a[mi][0] = ldA(A1L, mi, 0); a[mi][1] = ldA(A1L, mi, 1); }
#pragma unroll
    for (int nj = 0; nj < 2; ++nj) { b0[nj][0] = ldB(B1L, nj, 0); b0[nj][1] = ldB(B1L, nj, 1); }
    if (st) stB(B0L, 0, kt2);
    BAR();
    QUAD(b0, 0, 0);
    BAR();
    // ---- P6: buf1 quad(0,1) ------------------------------------------------
#pragma unroll
    for (int nj = 0; nj < 2; ++nj) { b1[nj][0] = ldB(B1L, 2 + nj, 0); b1[nj][1] = ldB(B1L, 2 + nj, 1); }
    if (st) stA(A1L, 0, kt3);
    BAR();
    QUAD(b1, 0, 1);
    BAR();
    // ---- P7: buf1 quad(1,1) ------------------------------------------------
#pragma unroll
    for (int mi = 0; mi < 4; ++mi) { a[mi][0] = ldA(A1L, 4 + mi, 0); a[mi][1] = ldA(A1L, 4 + mi, 1); }
    if (st) stB(B1L, 1, kt3);
    BAR();
    QUAD(b1, 1, 1);
    BAR();
    // ---- P8: buf1 quad(1,0); counted vmcnt ---------------------------------
    if (st) stA(A1L, 1, kt3);
    BAR();
    QUAD(b0, 1, 0);
    if (st) { WAITV6(); }
    BAR();
  }

  // ---- epilogue ------------------------------------------------------------
  const int cr = kg << 2;
  if (EPI == 2) {
    // scrambled window-reverse store -> PROJ2[b][c][h][w] bf16
#pragma unroll
    for (int ni = 0; ni < 4; ++ni) {
      const int ch = n0 + (wc << 6) + (ni << 4) + fr;
      const float bv = bias[ch];
      const int hlow = (ch >> 3) & 7;
      const int wmw = ((ch >> 6) & 7) << 3 | (ch & 7);
#pragma unroll
      for (int mi = 0; mi < 8; ++mi) {
#pragma unroll
        for (int rr = 0; rr < 4; ++rr) {
          const int m = m0 + (wr << 7) + (mi << 4) + cr + rr;
          const int b = m >> 14, tp = m & 16383;
          const int c = ((tp >> 6) << 1) | ((tp >> 5) & 1);
          const int h = (((tp >> 1) & 15) << 3) | hlow;
          const int w = ((tp & 1) << 6) | wmw;
          C[((size_t)(b * 512 + c) << 14) + (h << 7) + w] = f2bf(acc[mi][ni][rr] + bv);
        }
      }
    }
  } else {
#pragma unroll
    for (int ni = 0; ni < 4; ++ni) {
      const int col = n0 + (wc << 6) + (ni << 4) + fr;
      const float bv = bias[col];
#pragma unroll
      for (int mi = 0; mi < 8; ++mi) {
        const size_t base = (size_t)(m0 + (wr << 7) + (mi << 4) + cr) * N + col;
#pragma unroll
        for (int rr = 0; rr < 4; ++rr) {
          float v = acc[mi][ni][rr] + bv;
          if (EPI == 1) v = 0.5f * v * (1.0f + erff(v * 0.70710678118654752f));
          C[base + (size_t)rr * N] = f2bf(v);
        }
      }
    }
  }
}

// ---------------------------------------------------------------------------
// MFMA attention: one block per (window, head). 4 waves x 16 query rows.
// ---------------------------------------------------------------------------
__global__ __launch_bounds__(256) void attn_kernel(
    const ushort_t* __restrict__ QKV, const float* __restrict__ table,
    ushort_t* __restrict__ OUT) {
  const int w = blockIdx.x;            // window 0..2047
  const int h = blockIdx.y;            // head 0..15
  __shared__ __align__(16) ushort_t Vt[32][72];      // V^T, pad to 72 (144B rows)
  __shared__ __align__(16) ushort_t Pw[4][16][72];   // per-wave P rows
  __shared__ float bias_s[225];
  const int tid = threadIdx.x;
  const int wave = tid >> 6, lane = tid & 63;
  const int g = lane >> 4, c = lane & 15;

  if (tid < 225) bias_s[tid] = table[tid * 16 + h];

  const ushort_t* base = QKV + (size_t)(w << 6) * 1536 + h * 32;

  // ---- stage V^T: wave handles d-rows [wave*8, wave*8+8) --------------------
  {
    uint4 vv = *(const uint4*)(base + (size_t)lane * 1536 + 1024 + (wave << 3));
    const ushort_t* vp = (const ushort_t*)&vv;
#pragma unroll
    for (int e = 0; e < 8; ++e) Vt[(wave << 3) + e][lane] = vp[e];
  }

  // ---- Q fragment (A-layout) and 4 K fragments (B-layout) from global ------
  short8 qf = *(const short8*)(base + (size_t)((wave << 4) + c) * 1536 + (g << 3));
  short8 kf[4];
#pragma unroll
  for (int j = 0; j < 4; ++j)
    kf[j] = *(const short8*)(base + (size_t)((j << 4) + c) * 1536 + 512 + (g << 3));

  // ---- S = Q K^T -----------------------------------------------------------
  float4v acc[4];
#pragma unroll
  for (int j = 0; j < 4; ++j) {
#pragma unroll
    for (int r = 0; r < 4; ++r) acc[j][r] = 0.0f;
    acc[j] = __builtin_amdgcn_mfma_f32_16x16x32_bf16(qf, kf[j], acc[j], 0, 0, 0);
  }

  __syncthreads();   // bias_s + Vt ready

  // ---- scale + relative-position bias --------------------------------------
  const int q0 = (wave << 4) + (g << 2);
#pragma unroll
  for (int j = 0; j < 4; ++j) {
    const int k = (j << 4) + c;
    const int r2 = k >> 3, c2 = k & 7;
#pragma unroll
    for (int r = 0; r < 4; ++r) {
      const int qq = q0 + r;
      const int idx = ((qq >> 3) - r2 + 7) * 15 + ((qq & 7) - c2 + 7);
      acc[j][r] = acc[j][r] * 0.17677669529663689f + bias_s[idx];
    }
  }

  // ---- wave-parallel softmax over cols -------------------------------------
#pragma unroll
  for (int r = 0; r < 4; ++r) {
    float m = fmaxf(fmaxf(acc[0][r], acc[1][r]), fmaxf(acc[2][r], acc[3][r]));
    m = fmaxf(m, __shfl_xor(m, 1));
    m = fmaxf(m, __shfl_xor(m, 2));
    m = fmaxf(m, __shfl_xor(m, 4));
    m = fmaxf(m, __shfl_xor(m, 8));
    float s = 0.0f;
#pragma unroll
    for (int j = 0; j < 4; ++j) { acc[j][r] = __expf(acc[j][r] - m); s += acc[j][r]; }
    s += __shfl_xor(s, 1);
    s += __shfl_xor(s, 2);
    s += __shfl_xor(s, 4);
    s += __shfl_xor(s, 8);
    const float inv = 1.0f / s;
#pragma unroll
    for (int j = 0; j < 4; ++j)
      Pw[wave][(g << 2) + r][(j << 4) + c] = f2bf(acc[j][r] * inv);
  }

  __syncthreads();   // P writes visible

  // ---- O = P V -------------------------------------------------------------
  float4v oacc[2];
#pragma unroll
  for (int j2 = 0; j2 < 2; ++j2)
#pragma unroll
    for (int r = 0; r < 4; ++r) oacc[j2][r] = 0.0f;
#pragma unroll
  for (int ks = 0; ks < 2; ++ks) {
    short8 pa = *(const short8*)&Pw[wave][c][(ks << 5) + (g << 3)];
#pragma unroll
    for (int j2 = 0; j2 < 2; ++j2) {
      short8 vb = *(const short8*)&Vt[(j2 << 4) + c][(ks << 5) + (g << 3)];
      oacc[j2] = __builtin_amdgcn_mfma_f32_16x16x32_bf16(pa, vb, oacc[j2], 0, 0, 0);
    }
  }

  // ---- write O (token-major, col = h*32 + d) -------------------------------
  ushort_t* op = OUT + (size_t)((w << 6) + (wave << 4)) * 512 + h * 32;
#pragma unroll
  for (int j2 = 0; j2 < 2; ++j2)
#pragma unroll
    for (int r = 0; r < 4; ++r)
      op[(size_t)((g << 2) + r) * 512 + (j2 << 4) + c] = f2bf(oacc[j2][r]);
}

// ---------------------------------------------------------------------------
// x1 = x + PROJ2; XN2 = bf16(BN2(x1)), token-major.  PROJ2 is (B,C,H,W) bf16
// (scramble already applied by the proj GEMM epilogue) -> fully coalesced.
// ---------------------------------------------------------------------------
__global__ __launch_bounds__(256) void prep_mlp(
    const float* __restrict__ x, const ushort_t* __restrict__ PROJ2,
    const float* __restrict__ gamma, const float* __restrict__ beta,
    const float* __restrict__ mean, const float* __restrict__ var,
    ushort_t* __restrict__ XN2) {
  const int pc = blockIdx.x;           // 64 consecutive spatial positions
  const int cc0 = blockIdx.y << 5;
  const int p0 = pc << 6;
  const int b = p0 >> 14, hh = (p0 >> 7) & 127;
  __shared__ __align__(16) ushort_t tile[64][32];
  const int tid = threadIdx.x;
  const int ci = tid >> 3, wg = (tid & 7) << 3;
  const int c = cc0 + ci;
  const float a = gamma[c] * rsqrtf(var[c] + 1e-5f);
  const float sh = beta[c] - mean[c] * a;
  const int w0 = (p0 & 127) + wg;
  const size_t off = (((size_t)b * 512 + c) * 128 + hh) * 128 + w0;
  const float* xp = x + off;
  uint4 pv = *(const uint4*)(PROJ2 + off);
  const ushort_t* pu = (const ushort_t*)&pv;
#pragma unroll
  for (int j = 0; j < 8; ++j) {
    const float x1 = xp[j] + bf2f(pu[j]);
    tile[wg + j][ci] = f2bf(x1 * a + sh);
  }
  __syncthreads();
  const int i2 = tid >> 2, d0 = (tid & 3) << 3;
  *(uint4*)(XN2 + (size_t)(p0 + i2) * 512 + cc0 + d0) = *(const uint4*)&tile[i2][d0];
}

// out = x + PROJ2 + H2   (all reads coalesced; x1 recomputed in fp32)
__global__ __launch_bounds__(256) void final_add(
    const float* __restrict__ x, const ushort_t* __restrict__ PROJ2,
    const ushort_t* __restrict__ H2, float* __restrict__ out) {
  const int pc = blockIdx.x, cc0 = blockIdx.y << 5;
  const int p0 = pc << 6;
  const int b = p0 >> 14, hh = (p0 >> 7) & 127;
  __shared__ float tile[32][65];
  const int tid = threadIdx.x;
  {
    const int i2 = tid >> 2, d0 = (tid & 3) << 3;
    const ushort_t* hp = H2 + (size_t)(p0 + i2) * 512 + cc0 + d0;
#pragma unroll
    for (int j = 0; j < 8; ++j) tile[d0 + j][i2] = bf2f(hp[j]);
  }
  __syncthreads();
  const int ci = tid >> 3, wg = (tid & 7) << 3;
  const int c = cc0 + ci;
  const int w0 = (p0 & 127) + wg;
  const size_t off = (((size_t)b * 512 + c) * 128 + hh) * 128 + w0;
  const float* xp = x + off;
  float* op = out + off;
  uint4 pv = *(const uint4*)(PROJ2 + off);
  const ushort_t* pu = (const ushort_t*)&pv;
#pragma unroll
  for (int j = 0; j < 8; ++j)
    op[j] = xp[j] + bf2f(pu[j]) + tile[ci][wg + j];
}

// ---------------------------------------------------------------------------
extern "C" void kernel_launch(void* const* d_in, const int* in_sizes, int n_in,
                              void* d_out, int out_size, void* d_ws, size_t ws_size,
                              hipStream_t stream) {
  const float* x      = (const float*)d_in[0];
  const float* qkv_w  = (const float*)d_in[1];
  const float* qkv_b  = (const float*)d_in[2];
  const float* proj_w = (const float*)d_in[3];
  const float* proj_b = (const float*)d_in[4];
  const float* rel_t  = (const float*)d_in[5];
  const float* bn1g = (const float*)d_in[6];
  const float* bn1b = (const float*)d_in[7];
  const float* bn1m = (const float*)d_in[8];
  const float* bn1v = (const float*)d_in[9];
  const float* w1 = (const float*)d_in[10];
  const float* b1 = (const float*)d_in[11];
  const float* w2 = (const float*)d_in[12];
  const float* b2 = (const float*)d_in[13];
  const float* bn2g = (const float*)d_in[14];
  const float* bn2b = (const float*)d_in[15];
  const float* bn2m = (const float*)d_in[16];
  const float* bn2v = (const float*)d_in[17];
  float* out = (float*)d_out;

  char* ws = (char*)d_ws;
  const size_t SZ = (size_t)131072 * 512 * 2;           // 128 MB token-major bf16
  ushort_t* WQKV  = (ushort_t*)(ws);                    // 1536x512
  ushort_t* WPROJ = (ushort_t*)(ws + 1572864);          // 512x512
  ushort_t* W1B   = (ushort_t*)(ws + 2097152);
  ushort_t* W2B   = (ushort_t*)(ws + 2621440);
  ushort_t* A0    = (ushort_t*)(ws + 3145728);          // [131072,512]
  ushort_t* QKV   = (ushort_t*)(ws + 3145728 + SZ);     // [131072,1536]
  ushort_t* OUTB  = A0;                                 // attn out (A0 dead)
  ushort_t* PROJ2 = QKV;                                // QKV dead after attn; (B,C,H,W)
  ushort_t* XN2   = (ushort_t*)((char*)QKV + SZ);
  ushort_t* H1    = (ushort_t*)((char*)QKV + 2 * SZ);
  ushort_t* H2    = A0;                                 // OUTB dead after proj
  // peak ws use: 3145728 + 4*SZ = 540,016,640 bytes

  transpose_cast<<<(512 * 1536 + 255) / 256, 256, 0, stream>>>(qkv_w, WQKV, 512, 1536);
  transpose_cast<<<(512 * 512 + 255) / 256, 256, 0, stream>>>(proj_w, WPROJ, 512, 512);
  cast_bf<<<(512 * 512 + 255) / 256, 256, 0, stream>>>(w1, W1B, 512 * 512);
  cast_bf<<<(512 * 512 + 255) / 256, 256, 0, stream>>>(w2, W2B, 512 * 512);

  prep_qkv<<<dim3(2048, 16), 256, 0, stream>>>(x, bn1g, bn1b, bn1m, bn1v, A0);
  gemm256<0><<<dim3(6, 512), 512, 0, stream>>>(A0, WQKV, qkv_b, QKV, 131072, 1536, 512);
  attn_kernel<<<dim3(2048, 16), 256, 0, stream>>>(QKV, rel_t, OUTB);
  gemm256<2><<<dim3(2, 512), 512, 0, stream>>>(OUTB, WPROJ, proj_b, PROJ2, 131072, 512, 512);
  prep_mlp<<<dim3(2048, 16), 256, 0, stream>>>(x, PROJ2, bn2g, bn2b, bn2m, bn2v, XN2);
  gemm256<1><<<dim3(2, 512), 512, 0, stream>>>(XN2, W1B, b1, H1, 131072, 512, 512);
  gemm256<0><<<dim3(2, 512), 512, 0, stream>>>(H1, W2B, b2, H2, 131072, 512, 512);
  final_add<<<dim3(2048, 16), 256, 0, stream>>>(x, PROJ2, H2, out);
}